// Round 9
// baseline (338.515 us; speedup 1.0000x reference)
//
#include <hip/hip_runtime.h>
#include <stdint.h>

#define N_ROWS 4096
#define N_DIM  2048
#define MARGIN 0.3f
#define NTILE  32            // 4096 / 128 tiles per side
#define NITER  (N_DIM / 64)  // BK=64 -> 32 K-iterations
#define FLTMAX 3.402823466e+38f

typedef __attribute__((ext_vector_type(8))) short short8;
typedef __attribute__((ext_vector_type(4))) float floatx4;

// Packed layout ("fragment order"): for 16-row group b (256 total) and k-chunk
// c (32 k, 64 total), a 1 KB block at shorts-offset (b*64+c)*512. Lane l's
// 16 B fragment at l*8 shorts = row b*16+(l&15), k c*32+(l>>4)*8.. (verified
// absmax 0.0 in R1-R8).

__device__ inline unsigned short f2bf_rne(float f) {
  unsigned u = __float_as_uint(f);
  unsigned r = 0x7fffu + ((u >> 16) & 1u);
  return (unsigned short)((u + r) >> 16);
}
__device__ inline float bf2f(unsigned short h) {
  return __uint_as_float(((unsigned)h) << 16);
}

// Raw workgroup barrier WITHOUT the vmcnt(0) drain __syncthreads() emits.
// LDS visibility across the barrier needs only lgkmcnt(0) (ds_* completion);
// outstanding global_load -> VGPR traffic stays in flight (the whole point).
__device__ inline void barrier_lds_only() {
  asm volatile("s_waitcnt lgkmcnt(0)" ::: "memory");
  __builtin_amdgcn_s_barrier();
}

// ---------------------------------------------------------------------------
// Kernel 1: cast fp32 -> bf16 AND repack into fragment order; sq[i] from the
// ROUNDED values; init per-row reduction cells. One block per 16-row group.
// ---------------------------------------------------------------------------
__global__ __launch_bounds__(256) void prep_kernel(
    const float* __restrict__ X, unsigned short* __restrict__ Xp,
    float* __restrict__ sq, unsigned* __restrict__ ap, unsigned* __restrict__ an)
{
  const int b = blockIdx.x;
  const int t = threadIdx.x;
  const int r = t & 15, j = (t >> 4) & 3, w = t >> 6;
  const float* Xg = X + ((size_t)b * 16 + r) * N_DIM + j * 8;
  unsigned short* Op = Xp + (size_t)b * 64 * 512 + (size_t)(j * 16 + r) * 8;
  float acc = 0.f;
#pragma unroll
  for (int s = 0; s < 16; ++s) {
    const int c = w + s * 4;
    float4 v0 = *(const float4*)(Xg + c * 32);
    float4 v1 = *(const float4*)(Xg + c * 32 + 4);
    short8 o;
    o[0] = (short)f2bf_rne(v0.x); o[1] = (short)f2bf_rne(v0.y);
    o[2] = (short)f2bf_rne(v0.z); o[3] = (short)f2bf_rne(v0.w);
    o[4] = (short)f2bf_rne(v1.x); o[5] = (short)f2bf_rne(v1.y);
    o[6] = (short)f2bf_rne(v1.z); o[7] = (short)f2bf_rne(v1.w);
#pragma unroll
    for (int e = 0; e < 8; ++e) {
      float f = bf2f((unsigned short)o[e]);
      acc = fmaf(f, f, acc);
    }
    *(short8*)(Op + (size_t)c * 512) = o;
  }
  acc += __shfl_xor(acc, 16, 64);
  acc += __shfl_xor(acc, 32, 64);
  __shared__ float part[4][16];
  if ((t & 63) < 16) part[w][r] = acc;
  __syncthreads();
  if (t < 16) {
    float s4 = part[0][t] + part[1][t] + part[2][t] + part[3][t];
    sq[b * 16 + t] = s4;
    ap[b * 16 + t] = 0u;           // max identity (dist >= 0)
    an[b * 16 + t] = 0x7f7fffffu;  // FLT_MAX bits
  }
}

// ---------------------------------------------------------------------------
// Kernel 2: upper-triangle 128x128 tiles, LDS GEMM on the packed array, now
// with a 2-deep register pipeline across RAW barriers (no vmcnt drain):
//   invariant: at iter `it`, reg SET[(it+1)&1] holds tile it+1 (loaded a full
//   iteration ago -> its vmcnt wait at ds_write time is free).
//   iter body: issue loads(it+2) -> compute tile it from LDS -> store tile
//   it+1 -> lgkm-only barrier.  Tile k lives in LDS buf k&1; one barrier/iter
//   is sound (all waves pass barrier(it) before anyone rewrites buf cur).
// Staging identity chunk map (R8): conflict-free ds_write, coalesced 1 KB
// global reads. Each wave's 64x64 output feeds row-side AND (symmetry)
// col-side hardest-pos/neg reductions.
// ---------------------------------------------------------------------------
__global__ __launch_bounds__(256, 2) void dist_kernel(
    const unsigned short* __restrict__ Xp, const float* __restrict__ sq,
    const int* __restrict__ lab, unsigned* __restrict__ ap, unsigned* __restrict__ an)
{
  __shared__ __align__(16) unsigned short As[2][8192];   // 2 x 16 KB
  __shared__ __align__(16) unsigned short Bs[2][8192];   // 2 x 16 KB
  __shared__ float sqi[128], sqj[128];
  __shared__ int labi[128], labj[128];

  // decode linear block id -> (bi, bj) with bi <= bj
  int p = blockIdx.x;
  int bi = 0;
  while (p >= NTILE - bi) { p -= NTILE - bi; ++bi; }
  const int bj = bi + p;
  const bool offdiag = (bi != bj);

  const int t = threadIdx.x;
  const int lane = t & 63, w = t >> 6;     // 4 waves
  const int wm = w >> 1, wn = w & 1;       // 2x2 wave grid, 64x64 per wave

  if (t < 128) { int rr = bi * 128 + t; sqi[t] = sq[rr]; labi[t] = lab[rr]; }
  else         { int cc = bj * 128 + (t - 128); sqj[t - 128] = sq[cc]; labj[t - 128] = lab[cc]; }

  // identity chunk map: chunk c = q*256 + t, LDS shorts offset c*8 (16 B
  // lane-stride -> free 2-way bank aliasing), global: row-group c>>7,
  // 16 B-unit c&127, + it*1024 shorts per K-iter.
  unsigned gA[4], gB[4], lo[4];
#pragma unroll
  for (int q = 0; q < 4; ++q) {
    const unsigned c = q * 256 + t;
    const unsigned seg = c >> 7, off16 = c & 127;
    gA[q] = ((unsigned)(bi * 8 + seg) * 64) * 512 + off16 * 8;
    gB[q] = ((unsigned)(bj * 8 + seg) * 64) * 512 + off16 * 8;
    lo[q] = c * 8;
  }

  short8 ra[2][4], rb[2][4];               // two register sets (pipeline)
#define LOADG(SET, IT)                                                       \
  do {                                                                       \
    _Pragma("unroll")                                                        \
    for (int q = 0; q < 4; ++q) {                                            \
      ra[SET][q] = *(const short8*)(Xp + gA[q] + (unsigned)(IT) * 1024);     \
      if (offdiag) rb[SET][q] = *(const short8*)(Xp + gB[q] + (unsigned)(IT) * 1024); \
    }                                                                        \
  } while (0)
#define STORE(SET, BUF)                                                      \
  do {                                                                       \
    _Pragma("unroll")                                                        \
    for (int q = 0; q < 4; ++q) {                                            \
      *(short8*)&As[BUF][lo[q]] = ra[SET][q];                                \
      if (offdiag) *(short8*)&Bs[BUF][lo[q]] = rb[SET][q];                   \
    }                                                                        \
  } while (0)

  // prologue: tile0 -> LDS buf0 (via set0); tile1 -> set1 (stays in flight)
  LOADG(0, 0);
  STORE(0, 0);
  LOADG(1, 1);
  barrier_lds_only();

  floatx4 acc[4][4] = {};

  for (int it = 0; it < NITER; ++it) {
    const int cur = it & 1;
    if (it + 2 < NITER) LOADG(cur, it + 2);   // into SET[it&1] (free: its old
                                              // tile was stored last iter)
    const unsigned short* Asrc = As[cur];
    const unsigned short* Bsrc = offdiag ? Bs[cur] : As[cur];
#pragma unroll
    for (int kh = 0; kh < 2; ++kh) {
      short8 af[4], bfv[4];
#pragma unroll
      for (int mi = 0; mi < 4; ++mi)
        af[mi] = *(const short8*)&Asrc[((wm * 4 + mi) * 2 + kh) * 512 + lane * 8];
#pragma unroll
      for (int ni = 0; ni < 4; ++ni)
        bfv[ni] = *(const short8*)&Bsrc[((wn * 4 + ni) * 2 + kh) * 512 + lane * 8];
#pragma unroll
      for (int mi = 0; mi < 4; ++mi)
#pragma unroll
        for (int ni = 0; ni < 4; ++ni)
          acc[mi][ni] = __builtin_amdgcn_mfma_f32_16x16x32_bf16(
              af[mi], bfv[ni], acc[mi][ni], 0, 0, 0);
    }

    if (it + 1 < NITER) {
      STORE((it + 1) & 1, (it + 1) & 1);   // tile it+1 (landed long ago)
      barrier_lds_only();                  // lgkm drain only; vmcnt in flight
    }
  }
#undef LOADG
#undef STORE

  // Epilogue. C/D layout (m89): col = lane&15, row = (lane>>4)*4 + reg.
  const int cn = lane & 15, lg = lane >> 4;
  float sqc[4]; int labc[4];
#pragma unroll
  for (int ni = 0; ni < 4; ++ni) {
    int c = wn * 64 + ni * 16 + cn;
    sqc[ni] = sqj[c]; labc[ni] = labj[c];
  }
  float cap[4] = {0.f, 0.f, 0.f, 0.f};
  float can[4] = {FLTMAX, FLTMAX, FLTMAX, FLTMAX};
#pragma unroll
  for (int mi = 0; mi < 4; ++mi) {
#pragma unroll
    for (int r = 0; r < 4; ++r) {
      const int rl = wm * 64 + mi * 16 + lg * 4 + r;   // row within 128-tile
      const float si = sqi[rl];
      const int li = labi[rl];
      float apv = 0.0f;
      float anv = FLTMAX;
#pragma unroll
      for (int ni = 0; ni < 4; ++ni) {
        float g = acc[mi][ni][r];
        float d2 = fmaf(-2.0f, g, si + sqc[ni]);
        d2 = fmaxf(d2, 1e-12f);
        float d = __builtin_amdgcn_sqrtf(d2);
        const bool same = (li == labc[ni]);
        const float dp = same ? d : 0.0f;
        const float dn = same ? FLTMAX : d;
        apv = fmaxf(apv, dp);
        anv = fminf(anv, dn);
        cap[ni] = fmaxf(cap[ni], dp);   // col-side (symmetric) partials
        can[ni] = fminf(can[ni], dn);
      }
      // row side: reduce over the 16 cn-lanes (same lg = same row)
#pragma unroll
      for (int m = 8; m >= 1; m >>= 1) {
        apv = fmaxf(apv, __shfl_xor(apv, m, 64));
        anv = fminf(anv, __shfl_xor(anv, m, 64));
      }
      if (cn == 0) {
        int R = bi * 128 + rl;
        atomicMax(&ap[R], __float_as_uint(apv));
        atomicMin(&an[R], __float_as_uint(anv));
      }
    }
  }
  // col side: reduce over lg (xor 16,32) -> full 64 rows per column
#pragma unroll
  for (int ni = 0; ni < 4; ++ni) {
    float a = cap[ni], b = can[ni];
#pragma unroll
    for (int m = 16; m <= 32; m <<= 1) {
      a = fmaxf(a, __shfl_xor(a, m, 64));
      b = fminf(b, __shfl_xor(b, m, 64));
    }
    if (lg == 0) {
      int C = bj * 128 + wn * 64 + ni * 16 + cn;
      atomicMax(&ap[C], __float_as_uint(a));
      atomicMin(&an[C], __float_as_uint(b));
    }
  }
}

// ---------------------------------------------------------------------------
// Kernel 3: loss = mean(relu(margin + dist_ap - dist_an))
// ---------------------------------------------------------------------------
__global__ __launch_bounds__(256) void finalize_kernel(
    const unsigned* __restrict__ ap, const unsigned* __restrict__ an,
    float* __restrict__ out)
{
  const int t = threadIdx.x;
  float s = 0.f;
  for (int i = t; i < N_ROWS; i += 256) {
    float a = __uint_as_float(ap[i]);
    float b = __uint_as_float(an[i]);
    s += fmaxf(MARGIN + a - b, 0.0f);
  }
#pragma unroll
  for (int m = 32; m >= 1; m >>= 1) s += __shfl_down(s, m, 64);
  __shared__ float wsum[4];
  const int lane = t & 63, w = t >> 6;
  if (lane == 0) wsum[w] = s;
  __syncthreads();
  if (t == 0) out[0] = (wsum[0] + wsum[1] + wsum[2] + wsum[3]) * (1.0f / N_ROWS);
}

extern "C" void kernel_launch(void* const* d_in, const int* in_sizes, int n_in,
                              void* d_out, int out_size, void* d_ws, size_t ws_size,
                              hipStream_t stream) {
  const float* X = (const float*)d_in[0];
  const int* lab = (const int*)d_in[1];
  float* out = (float*)d_out;

  char* ws = (char*)d_ws;
  unsigned short* Xp = (unsigned short*)ws;                           // 16 MB packed
  float* sq  = (float*)(ws + (size_t)N_ROWS * N_DIM * 2);             // 16 KB
  unsigned* ap = (unsigned*)((char*)sq + N_ROWS * sizeof(float));     // 16 KB
  unsigned* an = (unsigned*)((char*)ap + N_ROWS * sizeof(unsigned));  // 16 KB

  prep_kernel<<<N_ROWS / 16, 256, 0, stream>>>(X, Xp, sq, ap, an);
  dist_kernel<<<NTILE * (NTILE + 1) / 2, 256, 0, stream>>>(Xp, sq, lab, ap, an);
  finalize_kernel<<<1, 256, 0, stream>>>(ap, an, out);
}

// Round 10
// 156.644 us; speedup vs baseline: 2.1611x; 2.1611x over previous
//
#include <hip/hip_runtime.h>
#include <stdint.h>

#define N_ROWS 4096
#define N_DIM  2048
#define MARGIN 0.3f
#define NTILE  32            // 4096 / 128 tiles per side
#define NITER  (N_DIM / 64)  // BK=64 -> 32 K-iterations (even)
#define FLTMAX 3.402823466e+38f

typedef __attribute__((ext_vector_type(8))) short short8;
typedef __attribute__((ext_vector_type(4))) float floatx4;

// Packed layout ("fragment order"): for 16-row group b (256 total) and k-chunk
// c (32 k, 64 total), a 1 KB block at shorts-offset (b*64+c)*512. Lane l's
// 16 B fragment at l*8 shorts = row b*16+(l&15), k c*32+(l>>4)*8.. (verified
// absmax 0.0 in R1-R9).

__device__ inline unsigned short f2bf_rne(float f) {
  unsigned u = __float_as_uint(f);
  unsigned r = 0x7fffu + ((u >> 16) & 1u);
  return (unsigned short)((u + r) >> 16);
}
__device__ inline float bf2f(unsigned short h) {
  return __uint_as_float(((unsigned)h) << 16);
}

// Raw workgroup barrier WITHOUT the vmcnt(0) drain __syncthreads() emits.
// LDS visibility needs only lgkmcnt(0); global loads stay in flight.
__device__ inline void barrier_lds_only() {
  asm volatile("s_waitcnt lgkmcnt(0)" ::: "memory");
  __builtin_amdgcn_s_barrier();
}

// ---------------------------------------------------------------------------
// Kernel 1: cast fp32 -> bf16 AND repack into fragment order; sq[i] from the
// ROUNDED values; init per-row reduction cells. One block per 16-row group.
// ---------------------------------------------------------------------------
__global__ __launch_bounds__(256) void prep_kernel(
    const float* __restrict__ X, unsigned short* __restrict__ Xp,
    float* __restrict__ sq, unsigned* __restrict__ ap, unsigned* __restrict__ an)
{
  const int b = blockIdx.x;
  const int t = threadIdx.x;
  const int r = t & 15, j = (t >> 4) & 3, w = t >> 6;
  const float* Xg = X + ((size_t)b * 16 + r) * N_DIM + j * 8;
  unsigned short* Op = Xp + (size_t)b * 64 * 512 + (size_t)(j * 16 + r) * 8;
  float acc = 0.f;
#pragma unroll
  for (int s = 0; s < 16; ++s) {
    const int c = w + s * 4;
    float4 v0 = *(const float4*)(Xg + c * 32);
    float4 v1 = *(const float4*)(Xg + c * 32 + 4);
    short8 o;
    o[0] = (short)f2bf_rne(v0.x); o[1] = (short)f2bf_rne(v0.y);
    o[2] = (short)f2bf_rne(v0.z); o[3] = (short)f2bf_rne(v0.w);
    o[4] = (short)f2bf_rne(v1.x); o[5] = (short)f2bf_rne(v1.y);
    o[6] = (short)f2bf_rne(v1.z); o[7] = (short)f2bf_rne(v1.w);
#pragma unroll
    for (int e = 0; e < 8; ++e) {
      float f = bf2f((unsigned short)o[e]);
      acc = fmaf(f, f, acc);
    }
    *(short8*)(Op + (size_t)c * 512) = o;
  }
  acc += __shfl_xor(acc, 16, 64);
  acc += __shfl_xor(acc, 32, 64);
  __shared__ float part[4][16];
  if ((t & 63) < 16) part[w][r] = acc;
  __syncthreads();
  if (t < 16) {
    float s4 = part[0][t] + part[1][t] + part[2][t] + part[3][t];
    sq[b * 16 + t] = s4;
    ap[b * 16 + t] = 0u;           // max identity (dist >= 0)
    an[b * 16 + t] = 0x7f7fffffu;  // FLT_MAX bits
  }
}

// ---------------------------------------------------------------------------
// Kernel 2: upper-triangle 128x128 tiles, LDS GEMM, 2-deep register pipeline
// across lgkm-only barriers. R9's fatal flaw fixed: the K-loop is manually
// unrolled x2 so ALL register-set / LDS-buffer indices are COMPILE-TIME
// constants (R9's runtime-indexed ra[cur][q] demoted the arrays to scratch:
// WRITE_SIZE 5->517 MB).
//   invariant entering sub-iter k (even): set0 free, set1 holds tile k+1,
//   buf0 holds tile k. Body: load(k+2)->set0; compute buf0; store set1->buf1;
//   barrier. Then swap roles for k+1.
// ds_write of tile k+1 waits (compiler vmcnt(N)) only on its own loads,
// issued a full compute-phase ago; the it+2 loads stay in flight across the
// barrier. Staging: identity chunk map (conflict-free LDS, coalesced 1 KB
// global reads). Each wave's 64x64 output feeds row-side AND (symmetry)
// col-side hardest-pos/neg reductions.
// ---------------------------------------------------------------------------
__global__ __launch_bounds__(256, 2) void dist_kernel(
    const unsigned short* __restrict__ Xp, const float* __restrict__ sq,
    const int* __restrict__ lab, unsigned* __restrict__ ap, unsigned* __restrict__ an)
{
  __shared__ __align__(16) unsigned short As[2][8192];   // 2 x 16 KB
  __shared__ __align__(16) unsigned short Bs[2][8192];   // 2 x 16 KB
  __shared__ float sqi[128], sqj[128];
  __shared__ int labi[128], labj[128];

  // decode linear block id -> (bi, bj) with bi <= bj
  int p = blockIdx.x;
  int bi = 0;
  while (p >= NTILE - bi) { p -= NTILE - bi; ++bi; }
  const int bj = bi + p;
  const bool offdiag = (bi != bj);

  const int t = threadIdx.x;
  const int lane = t & 63, w = t >> 6;     // 4 waves
  const int wm = w >> 1, wn = w & 1;       // 2x2 wave grid, 64x64 per wave

  if (t < 128) { int rr = bi * 128 + t; sqi[t] = sq[rr]; labi[t] = lab[rr]; }
  else         { int cc = bj * 128 + (t - 128); sqj[t - 128] = sq[cc]; labj[t - 128] = lab[cc]; }

  // identity chunk map: chunk c = q*256 + t, LDS shorts offset c*8 (16 B
  // lane-stride -> free 2-way bank aliasing), global: row-group c>>7,
  // 16 B-unit c&127, + it*1024 shorts per K-iter.
  unsigned gA[4], gB[4], lo[4];
#pragma unroll
  for (int q = 0; q < 4; ++q) {
    const unsigned c = q * 256 + t;
    const unsigned seg = c >> 7, off16 = c & 127;
    gA[q] = ((unsigned)(bi * 8 + seg) * 64) * 512 + off16 * 8;
    gB[q] = ((unsigned)(bj * 8 + seg) * 64) * 512 + off16 * 8;
    lo[q] = c * 8;
  }

  // two register sets, SEPARATE variables (never runtime-indexed)
  short8 ra0[4], rb0[4], ra1[4], rb1[4];

#define LOADG(RA, RB, IT)                                                    \
  do {                                                                       \
    _Pragma("unroll")                                                        \
    for (int q = 0; q < 4; ++q) {                                            \
      RA[q] = *(const short8*)(Xp + gA[q] + (unsigned)(IT) * 1024);          \
      if (offdiag) RB[q] = *(const short8*)(Xp + gB[q] + (unsigned)(IT) * 1024); \
    }                                                                        \
  } while (0)
#define STORE(RA, RB, BUF)                                                   \
  do {                                                                       \
    _Pragma("unroll")                                                        \
    for (int q = 0; q < 4; ++q) {                                            \
      *(short8*)&As[BUF][lo[q]] = RA[q];                                     \
      if (offdiag) *(short8*)&Bs[BUF][lo[q]] = RB[q];                        \
    }                                                                        \
  } while (0)
#define COMPUTE(BUF)                                                         \
  do {                                                                       \
    const unsigned short* Asrc = As[BUF];                                    \
    const unsigned short* Bsrc = offdiag ? Bs[BUF] : As[BUF];                \
    _Pragma("unroll")                                                        \
    for (int kh = 0; kh < 2; ++kh) {                                         \
      short8 af[4], bfv[4];                                                  \
      _Pragma("unroll")                                                      \
      for (int mi = 0; mi < 4; ++mi)                                         \
        af[mi] = *(const short8*)&Asrc[((wm * 4 + mi) * 2 + kh) * 512 + lane * 8]; \
      _Pragma("unroll")                                                      \
      for (int ni = 0; ni < 4; ++ni)                                         \
        bfv[ni] = *(const short8*)&Bsrc[((wn * 4 + ni) * 2 + kh) * 512 + lane * 8]; \
      _Pragma("unroll")                                                      \
      for (int mi = 0; mi < 4; ++mi)                                         \
        _Pragma("unroll")                                                    \
        for (int ni = 0; ni < 4; ++ni)                                       \
          acc[mi][ni] = __builtin_amdgcn_mfma_f32_16x16x32_bf16(             \
              af[mi], bfv[ni], acc[mi][ni], 0, 0, 0);                        \
    }                                                                        \
  } while (0)

  floatx4 acc[4][4] = {};

  // prologue: tile0 -> buf0 (through set0); tile1 -> set1 (in flight)
  LOADG(ra0, rb0, 0);
  STORE(ra0, rb0, 0);
  LOADG(ra1, rb1, 1);
  barrier_lds_only();

  for (int it = 0; it < NITER; it += 2) {
    // even sub-iter: compute tile it (buf0); set1 holds tile it+1
    if (it + 2 < NITER) LOADG(ra0, rb0, it + 2);
    COMPUTE(0);
    STORE(ra1, rb1, 1);                    // tile it+1 -> buf1
    barrier_lds_only();
    // odd sub-iter: compute tile it+1 (buf1); set0 holds tile it+2
    if (it + 3 < NITER) LOADG(ra1, rb1, it + 3);
    COMPUTE(1);
    if (it + 2 < NITER) {
      STORE(ra0, rb0, 0);                  // tile it+2 -> buf0
      barrier_lds_only();
    }
  }
#undef LOADG
#undef STORE
#undef COMPUTE

  // Epilogue. C/D layout (m89): col = lane&15, row = (lane>>4)*4 + reg.
  const int cn = lane & 15, lg = lane >> 4;
  float sqc[4]; int labc[4];
#pragma unroll
  for (int ni = 0; ni < 4; ++ni) {
    int c = wn * 64 + ni * 16 + cn;
    sqc[ni] = sqj[c]; labc[ni] = labj[c];
  }
  float cap[4] = {0.f, 0.f, 0.f, 0.f};
  float can[4] = {FLTMAX, FLTMAX, FLTMAX, FLTMAX};
#pragma unroll
  for (int mi = 0; mi < 4; ++mi) {
#pragma unroll
    for (int r = 0; r < 4; ++r) {
      const int rl = wm * 64 + mi * 16 + lg * 4 + r;   // row within 128-tile
      const float si = sqi[rl];
      const int li = labi[rl];
      float apv = 0.0f;
      float anv = FLTMAX;
#pragma unroll
      for (int ni = 0; ni < 4; ++ni) {
        float g = acc[mi][ni][r];
        float d2 = fmaf(-2.0f, g, si + sqc[ni]);
        d2 = fmaxf(d2, 1e-12f);
        float d = __builtin_amdgcn_sqrtf(d2);
        const bool same = (li == labc[ni]);
        const float dp = same ? d : 0.0f;
        const float dn = same ? FLTMAX : d;
        apv = fmaxf(apv, dp);
        anv = fminf(anv, dn);
        cap[ni] = fmaxf(cap[ni], dp);   // col-side (symmetric) partials
        can[ni] = fminf(can[ni], dn);
      }
      // row side: reduce over the 16 cn-lanes (same lg = same row)
#pragma unroll
      for (int m = 8; m >= 1; m >>= 1) {
        apv = fmaxf(apv, __shfl_xor(apv, m, 64));
        anv = fminf(anv, __shfl_xor(anv, m, 64));
      }
      if (cn == 0) {
        int R = bi * 128 + rl;
        atomicMax(&ap[R], __float_as_uint(apv));
        atomicMin(&an[R], __float_as_uint(anv));
      }
    }
  }
  // col side: reduce over lg (xor 16,32) -> full 64 rows per column
#pragma unroll
  for (int ni = 0; ni < 4; ++ni) {
    float a = cap[ni], b = can[ni];
#pragma unroll
    for (int m = 16; m <= 32; m <<= 1) {
      a = fmaxf(a, __shfl_xor(a, m, 64));
      b = fminf(b, __shfl_xor(b, m, 64));
    }
    if (lg == 0) {
      int C = bj * 128 + wn * 64 + ni * 16 + cn;
      atomicMax(&ap[C], __float_as_uint(a));
      atomicMin(&an[C], __float_as_uint(b));
    }
  }
}

// ---------------------------------------------------------------------------
// Kernel 3: loss = mean(relu(margin + dist_ap - dist_an))
// ---------------------------------------------------------------------------
__global__ __launch_bounds__(256) void finalize_kernel(
    const unsigned* __restrict__ ap, const unsigned* __restrict__ an,
    float* __restrict__ out)
{
  const int t = threadIdx.x;
  float s = 0.f;
  for (int i = t; i < N_ROWS; i += 256) {
    float a = __uint_as_float(ap[i]);
    float b = __uint_as_float(an[i]);
    s += fmaxf(MARGIN + a - b, 0.0f);
  }
#pragma unroll
  for (int m = 32; m >= 1; m >>= 1) s += __shfl_down(s, m, 64);
  __shared__ float wsum[4];
  const int lane = t & 63, w = t >> 6;
  if (lane == 0) wsum[w] = s;
  __syncthreads();
  if (t == 0) out[0] = (wsum[0] + wsum[1] + wsum[2] + wsum[3]) * (1.0f / N_ROWS);
}

extern "C" void kernel_launch(void* const* d_in, const int* in_sizes, int n_in,
                              void* d_out, int out_size, void* d_ws, size_t ws_size,
                              hipStream_t stream) {
  const float* X = (const float*)d_in[0];
  const int* lab = (const int*)d_in[1];
  float* out = (float*)d_out;

  char* ws = (char*)d_ws;
  unsigned short* Xp = (unsigned short*)ws;                           // 16 MB packed
  float* sq  = (float*)(ws + (size_t)N_ROWS * N_DIM * 2);             // 16 KB
  unsigned* ap = (unsigned*)((char*)sq + N_ROWS * sizeof(float));     // 16 KB
  unsigned* an = (unsigned*)((char*)ap + N_ROWS * sizeof(unsigned));  // 16 KB

  prep_kernel<<<N_ROWS / 16, 256, 0, stream>>>(X, Xp, sq, ap, an);
  dist_kernel<<<NTILE * (NTILE + 1) / 2, 256, 0, stream>>>(Xp, sq, lab, ap, an);
  finalize_kernel<<<1, 256, 0, stream>>>(ap, an, out);
}